// Round 1
// baseline (94.406 us; speedup 1.0000x reference)
//
#include <hip/hip_runtime.h>

#define BATCH 524288
#define TPB 256
#define V 2   // samples per thread

// ---------------------------------------------------------------------------
// Fused kernel: threads 0..15 of each block rebuild the weight-only 16x16
// unitary U into LDS (thread t evolves basis column t; writes transposed so
// Ush[j*32+k]=Re U[j][k], Ush[j*32+16+k]=Im U[j][k]).  One barrier, then the
// per-sample hot path reads U rows as uniform ds_read_b128 broadcasts.
// Removes the qprep kernel launch + graph serialization + d_ws round-trip.
//
// Epilogue trick: U unitary + normalized input => sum_j p_j == 1, so
// z_i = 1 - 2*sum_{j: bit_i(j)=1} p_j.  Row j=0 is never needed (saves 32
// FMAs + 2 VALU per sample) and sign-accumulate is 32 adds instead of 64.
// ---------------------------------------------------------------------------
__global__ __launch_bounds__(TPB, 4) void qfused_kernel(const float* __restrict__ x,
                                                        const float* __restrict__ w,
                                                        float* __restrict__ out) {
    __shared__ __align__(16) float Ush[512];
    const int tid = threadIdx.x;

    if (tid < 16) {
        float stx[16], sty[16];
        #pragma unroll
        for (int i = 0; i < 16; i++) { stx[i] = 0.f; sty[i] = 0.f; }
        stx[tid] = 1.f;

        #pragma unroll
        for (int l = 0; l < 2; l++) {
            #pragma unroll
            for (int q = 0; q < 4; q++) {
                float cz, sz, cy, sy;
                __sincosf(0.5f * w[l * 8 + q * 2 + 0], &sz, &cz);
                __sincosf(0.5f * w[l * 8 + q * 2 + 1], &sy, &cy);
                const int mask = 8 >> q;
                // RZ(t) = diag(e^{-it/2}, e^{+it/2})
                #pragma unroll
                for (int i = 0; i < 16; i++) {
                    float ax = stx[i], ay = sty[i];
                    if (i & mask) { stx[i] = ax * cz - ay * sz; sty[i] = ay * cz + ax * sz; }
                    else          { stx[i] = ax * cz + ay * sz; sty[i] = ay * cz - ax * sz; }
                }
                // RY(t) = [[c,-s],[s,c]]
                #pragma unroll
                for (int i = 0; i < 16; i++) {
                    if (!(i & mask)) {
                        float a0x = stx[i], a0y = sty[i];
                        float a1x = stx[i | mask], a1y = sty[i | mask];
                        stx[i]        = cy * a0x - sy * a1x;
                        sty[i]        = cy * a0y - sy * a1y;
                        stx[i | mask] = sy * a0x + cy * a1x;
                        sty[i | mask] = sy * a0y + cy * a1y;
                    }
                }
            }
            // CNOT ring (0,1),(1,2),(2,3),(3,0); wire 0 is MSB (bit 3)
            #pragma unroll
            for (int e = 0; e < 4; e++) {
                const int cqs[4] = {0, 1, 2, 3};
                const int tqs[4] = {1, 2, 3, 0};
                const int cm = 8 >> cqs[e];
                const int tm = 8 >> tqs[e];
                #pragma unroll
                for (int i = 0; i < 16; i++) {
                    if ((i & cm) && !(i & tm)) {
                        float t0x = stx[i], t0y = sty[i];
                        stx[i] = stx[i | tm]; sty[i] = sty[i | tm];
                        stx[i | tm] = t0x;    sty[i | tm] = t0y;
                    }
                }
            }
        }
        #pragma unroll
        for (int j = 0; j < 16; j++) {
            Ush[j * 32 + tid]      = stx[j];   // Re U[j][tid]
            Ush[j * 32 + 16 + tid] = sty[j];   // Im U[j][tid]
        }
    }
    __syncthreads();

    const int base = blockIdx.x * (TPB * V) + tid;

    // Initial state after RY(x) encoding is a real product state:
    // sv = (c0,s0)x(c1,s1)x(c2,s2)x(c3,s3)
    float sv[V][16];
    #pragma unroll
    for (int v = 0; v < V; v++) {
        const int smp = base + v * TPB;
        const float4 xv = reinterpret_cast<const float4*>(x)[smp];
        float c0, s0, c1, s1, c2, s2, c3, s3;
        __sincosf(0.5f * xv.x, &s0, &c0);
        __sincosf(0.5f * xv.y, &s1, &c1);
        __sincosf(0.5f * xv.z, &s2, &c2);
        __sincosf(0.5f * xv.w, &s3, &c3);
        const float p01[4] = {c0 * c1, c0 * s1, s0 * c1, s0 * s1};
        const float p23[4] = {c2 * c3, c2 * s3, s2 * c3, s2 * s3};
        #pragma unroll
        for (int i = 0; i < 16; i++) sv[v][i] = p01[i >> 2] * p23[i & 3];
    }

    float acc[V][4];
    #pragma unroll
    for (int v = 0; v < V; v++)
        #pragma unroll
        for (int i = 0; i < 4; i++) acc[v][i] = 0.f;

    // Rows j=1..15 only; z_i = 1 - 2 * sum_{j: bit_i set} |amp_j|^2
    #pragma unroll
    for (int j = 1; j < 16; j++) {
        float ur[16], ui[16];
        #pragma unroll
        for (int t = 0; t < 4; t++) {
            const float4 a = reinterpret_cast<const float4*>(Ush + j * 32)[t];
            ur[4 * t + 0] = a.x; ur[4 * t + 1] = a.y; ur[4 * t + 2] = a.z; ur[4 * t + 3] = a.w;
            const float4 b = reinterpret_cast<const float4*>(Ush + j * 32 + 16)[t];
            ui[4 * t + 0] = b.x; ui[4 * t + 1] = b.y; ui[4 * t + 2] = b.z; ui[4 * t + 3] = b.w;
        }
        #pragma unroll
        for (int v = 0; v < V; v++) {
            float re = 0.f, im = 0.f;
            #pragma unroll
            for (int k = 0; k < 16; k++) {
                re = fmaf(ur[k], sv[v][k], re);
                im = fmaf(ui[k], sv[v][k], im);
            }
            const float p = fmaf(re, re, im * im);
            if (j & 8) acc[v][0] += p;
            if (j & 4) acc[v][1] += p;
            if (j & 2) acc[v][2] += p;
            if (j & 1) acc[v][3] += p;
        }
    }

    #pragma unroll
    for (int v = 0; v < V; v++) {
        const int smp = base + v * TPB;
        reinterpret_cast<float4*>(out)[smp] =
            make_float4(fmaf(-2.f, acc[v][0], 1.f), fmaf(-2.f, acc[v][1], 1.f),
                        fmaf(-2.f, acc[v][2], 1.f), fmaf(-2.f, acc[v][3], 1.f));
    }
}

extern "C" void kernel_launch(void* const* d_in, const int* in_sizes, int n_in,
                              void* d_out, int out_size, void* d_ws, size_t ws_size,
                              hipStream_t stream) {
    const float* x = (const float*)d_in[0];
    const float* w = (const float*)d_in[1];
    float* out = (float*)d_out;
    const int grid = BATCH / (TPB * V);  // 1024 blocks
    qfused_kernel<<<grid, TPB, 0, stream>>>(x, w, out);
}

// Round 2
// 69.554 us; speedup vs baseline: 1.3573x; 1.3573x over previous
//
#include <hip/hip_runtime.h>

#define BATCH 524288
#define TPB 256

typedef _Float16 half8 __attribute__((ext_vector_type(8)));
typedef float f32x4 __attribute__((ext_vector_type(4)));

// ---------------------------------------------------------------------------
// Kernel 1 (tiny, unchanged from the 68.8us baseline): build the weight-only
// 16x16 unitary U, write to d_ws row-major: ws[j*32+k]=Re U[j][k],
// ws[j*32+16+k]=Im U[j][k]. Thread k evolves basis column k.
// ---------------------------------------------------------------------------
__global__ void qprep_kernel(const float* __restrict__ w, float* __restrict__ ws) {
    const int tid = threadIdx.x;
    if (tid >= 16) return;

    float stx[16], sty[16];
    #pragma unroll
    for (int i = 0; i < 16; i++) { stx[i] = 0.f; sty[i] = 0.f; }
    stx[tid] = 1.f;

    #pragma unroll
    for (int l = 0; l < 2; l++) {
        #pragma unroll
        for (int q = 0; q < 4; q++) {
            float cz, sz, cy, sy;
            __sincosf(0.5f * w[l * 8 + q * 2 + 0], &sz, &cz);
            __sincosf(0.5f * w[l * 8 + q * 2 + 1], &sy, &cy);
            const int mask = 8 >> q;
            #pragma unroll
            for (int i = 0; i < 16; i++) {
                float ax = stx[i], ay = sty[i];
                if (i & mask) { stx[i] = ax * cz - ay * sz; sty[i] = ay * cz + ax * sz; }
                else          { stx[i] = ax * cz + ay * sz; sty[i] = ay * cz - ax * sz; }
            }
            #pragma unroll
            for (int i = 0; i < 16; i++) {
                if (!(i & mask)) {
                    float a0x = stx[i], a0y = sty[i];
                    float a1x = stx[i | mask], a1y = sty[i | mask];
                    stx[i]        = cy * a0x - sy * a1x;
                    sty[i]        = cy * a0y - sy * a1y;
                    stx[i | mask] = sy * a0x + cy * a1x;
                    sty[i | mask] = sy * a0y + cy * a1y;
                }
            }
        }
        #pragma unroll
        for (int e = 0; e < 4; e++) {
            const int cqs[4] = {0, 1, 2, 3};
            const int tqs[4] = {1, 2, 3, 0};
            const int cm = 8 >> cqs[e];
            const int tm = 8 >> tqs[e];
            #pragma unroll
            for (int i = 0; i < 16; i++) {
                if ((i & cm) && !(i & tm)) {
                    float t0x = stx[i], t0y = sty[i];
                    stx[i] = stx[i | tm]; sty[i] = sty[i | tm];
                    stx[i | tm] = t0x;    sty[i | tm] = t0y;
                }
            }
        }
    }
    #pragma unroll
    for (int j = 0; j < 16; j++) {
        ws[j * 32 + tid]      = stx[j];
        ws[j * 32 + 16 + tid] = sty[j];
    }
}

// ---------------------------------------------------------------------------
// Kernel 2 (hot), MFMA rewrite.
// D[j][s] = sum_k U[j][k] * S[s][k] via v_mfma_f32_16x16x32_f16, K=32 used as
// [S_hi | S_lo] (exact f16 split of the f32 state). Two accumulating MFMAs per
// component: A=[U_hi|U_hi] then A=[U_lo|U_lo] ->  S*(U_hi+U_lo) = S*U with
// ~2^-22 residual. A-frags are constant per lane (loaded once from d_ws).
// C/D layout (HW-verified): col(sample)=lane&15, row(j)=(lane>>4)*4+reg.
//   -> p = re^2+im^2 needs NO cross-lane pairing; the 4 <Z_i> are a 7-op
//      per-lane combine + 2 shfl_xor butterfly stages (signs of Z0/Z1 depend
//      only on lane-group, Z2/Z3 only on reg index).
// LDS: 256 rows x 64B (hi[0..15]|lo[0..15] as f16), 16B chunks XOR-swizzled
// (chunk ^= (row>>1)&3) so both write and A.. B-frag read run near the LDS
// bandwidth floor. Waves only touch their own 64 rows; __syncthreads once.
// ---------------------------------------------------------------------------
__global__ __launch_bounds__(TPB, 4) void qmain_kernel(const float* __restrict__ x,
                                                       const float* __restrict__ U,
                                                       float* __restrict__ out) {
    __shared__ __align__(16) _Float16 Sb[TPB * 32];   // 16 KB

    const int tid  = threadIdx.x;
    const int lane = tid & 63;
    const int wave = tid >> 6;
    const int l15  = lane & 15;
    const int lg   = lane >> 4;

    // ---- constant A-operand fragments: lane holds U[j=l15][k8..k8+7], k8=(lg&1)*8
    const int k8 = (lg & 1) * 8;
    const float* urow = U + l15 * 32 + k8;
    const float4 r0 = *reinterpret_cast<const float4*>(urow);
    const float4 r1 = *reinterpret_cast<const float4*>(urow + 4);
    const float4 i0 = *reinterpret_cast<const float4*>(urow + 16);
    const float4 i1 = *reinterpret_cast<const float4*>(urow + 20);
    const float ur[8] = {r0.x, r0.y, r0.z, r0.w, r1.x, r1.y, r1.z, r1.w};
    const float ui[8] = {i0.x, i0.y, i0.z, i0.w, i1.x, i1.y, i1.z, i1.w};
    half8 a_rh, a_rl, a_ih, a_il;
    #pragma unroll
    for (int i = 0; i < 8; i++) {
        const _Float16 h = (_Float16)ur[i];
        a_rh[i] = h;
        a_rl[i] = (_Float16)(ur[i] - (float)h);
        const _Float16 g = (_Float16)ui[i];
        a_ih[i] = g;
        a_il[i] = (_Float16)(ui[i] - (float)g);
    }

    // ---- per-thread: one sample's product state -> f16 hi/lo -> LDS
    const int samp = blockIdx.x * TPB + tid;
    const float4 xv = reinterpret_cast<const float4*>(x)[samp];
    float c0, s0, c1, s1, c2, s2, c3, s3;
    __sincosf(0.5f * xv.x, &s0, &c0);
    __sincosf(0.5f * xv.y, &s1, &c1);
    __sincosf(0.5f * xv.z, &s2, &c2);
    __sincosf(0.5f * xv.w, &s3, &c3);
    const float p01[4] = {c0 * c1, c0 * s1, s0 * c1, s0 * s1};
    const float p23[4] = {c2 * c3, c2 * s3, s2 * c3, s2 * s3};
    half8 ch[4];  // 0,1 = hi[0..7],hi[8..15]; 2,3 = lo[0..7],lo[8..15]
    #pragma unroll
    for (int i = 0; i < 16; i++) {
        const float sv = p01[i >> 2] * p23[i & 3];
        const _Float16 h = (_Float16)sv;
        ch[i >> 3][i & 7]       = h;
        ch[2 + (i >> 3)][i & 7] = (_Float16)(sv - (float)h);
    }
    {
        _Float16* rowp = Sb + tid * 32;
        const int swz = (tid >> 1) & 3;
        #pragma unroll
        for (int c = 0; c < 4; c++)
            *reinterpret_cast<half8*>(rowp + ((c ^ swz) * 8)) = ch[c];
    }
    __syncthreads();

    // ---- each wave: 4 MFMA tiles over its own 64 samples
    const int rs = lg ^ ((l15 >> 1) & 3);                    // lane-constant read swizzle
    const _Float16* rp = Sb + (wave * 64 + l15) * 32 + rs * 8;
    const int obase = blockIdx.x * TPB + wave * 64;

    #pragma unroll
    for (int T = 0; T < 4; T++) {
        const half8 b = *reinterpret_cast<const half8*>(rp + T * 512);
        f32x4 cre = {0.f, 0.f, 0.f, 0.f}, cim = {0.f, 0.f, 0.f, 0.f};
        cre = __builtin_amdgcn_mfma_f32_16x16x32_f16(a_rh, b, cre, 0, 0, 0);
        cre = __builtin_amdgcn_mfma_f32_16x16x32_f16(a_rl, b, cre, 0, 0, 0);
        cim = __builtin_amdgcn_mfma_f32_16x16x32_f16(a_ih, b, cim, 0, 0, 0);
        cim = __builtin_amdgcn_mfma_f32_16x16x32_f16(a_il, b, cim, 0, 0, 0);

        // p_r = |amp_{j=4*lg+r}|^2 for sample s=l15
        const float q0 = fmaf(cre[0], cre[0], cim[0] * cim[0]);
        const float q1 = fmaf(cre[1], cre[1], cim[1] * cim[1]);
        const float q2 = fmaf(cre[2], cre[2], cim[2] * cim[2]);
        const float q3 = fmaf(cre[3], cre[3], cim[3] * cim[3]);
        // j = 4*lg + r:  bit3(j)=lg&2, bit2(j)=lg&1, bit1(j)=r&2, bit0(j)=r&1
        const float s01 = q0 + q1, s23 = q2 + q3;
        const float t = s01 + s23;                 // sum over r
        const float u = s01 - s23;                 // Z2 partial (sign by r&2)
        const float v = (q0 - q1) + (q2 - q3);     // Z3 partial (sign by r&1)
        // stage 1: xor 16 (lg^1)
        const float tx = __shfl_xor(t, 16);
        const float t1 = t + tx;
        const float z1 = t - tx;                   // valid in lg even
        const float u1 = u + __shfl_xor(u, 16);
        const float v1 = v + __shfl_xor(v, 16);
        // stage 2: xor 32 (lg^2); results valid in lanes 0..15 (lg=0), which store
        const float z0  = t1 - __shfl_xor(t1, 32);
        const float z1f = z1 + __shfl_xor(z1, 32);
        const float z2  = u1 + __shfl_xor(u1, 32);
        const float z3  = v1 + __shfl_xor(v1, 32);

        if (lane < 16)
            reinterpret_cast<float4*>(out)[obase + T * 16 + l15] =
                make_float4(z0, z1f, z2, z3);
    }
}

extern "C" void kernel_launch(void* const* d_in, const int* in_sizes, int n_in,
                              void* d_out, int out_size, void* d_ws, size_t ws_size,
                              hipStream_t stream) {
    const float* x = (const float*)d_in[0];
    const float* w = (const float*)d_in[1];
    float* out = (float*)d_out;
    float* U = (float*)d_ws;  // 512 floats

    qprep_kernel<<<1, 64, 0, stream>>>(w, U);
    const int grid = BATCH / TPB;  // 2048 blocks, 1 sample/thread
    qmain_kernel<<<grid, TPB, 0, stream>>>(x, U, out);
}

// Round 3
// 67.408 us; speedup vs baseline: 1.4005x; 1.0318x over previous
//
#include <hip/hip_runtime.h>

#define BATCH 524288
#define TPB 256

typedef _Float16 half8 __attribute__((ext_vector_type(8)));
typedef float f32x4 __attribute__((ext_vector_type(4)));

// ---------------------------------------------------------------------------
// Single fused kernel (removes the serialized 1-block qprep dispatch).
//
// Phase A (threads 0..15 of wave 0): evolve basis column tid through the
//   weight-only circuit -> Ub[j*36 + tid] = Re U[j][tid], [+16] = Im.
//   Row stride 36 floats keeps float4 alignment and <=2-way bank aliasing
//   for the post-barrier fragment read. U regs (stx/sty) die before phase C.
// Phase B (all threads): per-sample product state -> exact f16 hi/lo split
//   -> swizzled LDS rows (16B chunks, chunk ^= (row>>1)&3).
// ONE barrier.
// Phase C: A-fragments from Ub (4x ds_read_b128 per lane, one time), then
//   per wave 4 MFMA tiles (v_mfma_f32_16x16x32_f16, K=32 = [S_hi|S_lo],
//   A = [U_hi|U_hi] then [U_lo|U_lo] accumulating -> exact-to-2^-22 S*U).
//   C/D layout: col(sample)=lane&15, row(j)=(lane>>4)*4+reg. p=re^2+im^2 is
//   lane-local; <Z_i> = 7-op per-lane combine + 2 shfl_xor stages; lanes<16
//   store float4.
// ---------------------------------------------------------------------------
__global__ __launch_bounds__(TPB, 4) void qfused_kernel(const float* __restrict__ x,
                                                        const float* __restrict__ w,
                                                        float* __restrict__ out) {
    __shared__ __align__(16) float    Ub[16 * 36];   // 2.25 KB
    __shared__ __align__(16) _Float16 Sb[TPB * 32];  // 16 KB

    const int tid  = threadIdx.x;
    const int lane = tid & 63;
    const int wave = tid >> 6;
    const int l15  = lane & 15;
    const int lg   = lane >> 4;

    // ---- Phase A: build U columns (16 builder threads)
    if (tid < 16) {
        float stx[16], sty[16];
        #pragma unroll
        for (int i = 0; i < 16; i++) { stx[i] = 0.f; sty[i] = 0.f; }
        stx[tid] = 1.f;

        #pragma unroll
        for (int l = 0; l < 2; l++) {
            #pragma unroll
            for (int q = 0; q < 4; q++) {
                float cz, sz, cy, sy;
                __sincosf(0.5f * w[l * 8 + q * 2 + 0], &sz, &cz);
                __sincosf(0.5f * w[l * 8 + q * 2 + 1], &sy, &cy);
                const int mask = 8 >> q;
                // RZ(t) = diag(e^{-it/2}, e^{+it/2})
                #pragma unroll
                for (int i = 0; i < 16; i++) {
                    float ax = stx[i], ay = sty[i];
                    if (i & mask) { stx[i] = ax * cz - ay * sz; sty[i] = ay * cz + ax * sz; }
                    else          { stx[i] = ax * cz + ay * sz; sty[i] = ay * cz - ax * sz; }
                }
                // RY(t) = [[c,-s],[s,c]]
                #pragma unroll
                for (int i = 0; i < 16; i++) {
                    if (!(i & mask)) {
                        float a0x = stx[i], a0y = sty[i];
                        float a1x = stx[i | mask], a1y = sty[i | mask];
                        stx[i]        = cy * a0x - sy * a1x;
                        sty[i]        = cy * a0y - sy * a1y;
                        stx[i | mask] = sy * a0x + cy * a1x;
                        sty[i | mask] = sy * a0y + cy * a1y;
                    }
                }
            }
            // CNOT ring (0,1),(1,2),(2,3),(3,0); wire 0 is MSB (bit 3)
            #pragma unroll
            for (int e = 0; e < 4; e++) {
                const int cqs[4] = {0, 1, 2, 3};
                const int tqs[4] = {1, 2, 3, 0};
                const int cm = 8 >> cqs[e];
                const int tm = 8 >> tqs[e];
                #pragma unroll
                for (int i = 0; i < 16; i++) {
                    if ((i & cm) && !(i & tm)) {
                        float t0x = stx[i], t0y = sty[i];
                        stx[i] = stx[i | tm]; sty[i] = sty[i | tm];
                        stx[i | tm] = t0x;    sty[i | tm] = t0y;
                    }
                }
            }
        }
        #pragma unroll
        for (int j = 0; j < 16; j++) {
            Ub[j * 36 + tid]      = stx[j];   // Re U[j][tid]
            Ub[j * 36 + 16 + tid] = sty[j];   // Im U[j][tid]
        }
    }

    // ---- Phase B: per-thread product state -> f16 hi/lo -> Sb
    const int samp = blockIdx.x * TPB + tid;
    const float4 xv = reinterpret_cast<const float4*>(x)[samp];
    float c0, s0, c1, s1, c2, s2, c3, s3;
    __sincosf(0.5f * xv.x, &s0, &c0);
    __sincosf(0.5f * xv.y, &s1, &c1);
    __sincosf(0.5f * xv.z, &s2, &c2);
    __sincosf(0.5f * xv.w, &s3, &c3);
    const float p01[4] = {c0 * c1, c0 * s1, s0 * c1, s0 * s1};
    const float p23[4] = {c2 * c3, c2 * s3, s2 * c3, s2 * s3};
    half8 ch[4];  // 0,1 = hi[0..7],hi[8..15]; 2,3 = lo[0..7],lo[8..15]
    #pragma unroll
    for (int i = 0; i < 16; i++) {
        const float sv = p01[i >> 2] * p23[i & 3];
        const _Float16 h = (_Float16)sv;
        ch[i >> 3][i & 7]       = h;
        ch[2 + (i >> 3)][i & 7] = (_Float16)(sv - (float)h);
    }
    {
        _Float16* rowp = Sb + tid * 32;
        const int swz = (tid >> 1) & 3;
        #pragma unroll
        for (int c = 0; c < 4; c++)
            *reinterpret_cast<half8*>(rowp + ((c ^ swz) * 8)) = ch[c];
    }
    __syncthreads();

    // ---- Phase C: A-fragments from Ub (one-time LDS read), then MFMA tiles
    const int k8 = (lg & 1) * 8;
    const float* urow = Ub + l15 * 36 + k8;
    const float4 r0 = *reinterpret_cast<const float4*>(urow);
    const float4 r1 = *reinterpret_cast<const float4*>(urow + 4);
    const float4 i0 = *reinterpret_cast<const float4*>(urow + 16);
    const float4 i1 = *reinterpret_cast<const float4*>(urow + 20);
    const float ur[8] = {r0.x, r0.y, r0.z, r0.w, r1.x, r1.y, r1.z, r1.w};
    const float ui[8] = {i0.x, i0.y, i0.z, i0.w, i1.x, i1.y, i1.z, i1.w};
    half8 a_rh, a_rl, a_ih, a_il;
    #pragma unroll
    for (int i = 0; i < 8; i++) {
        const _Float16 h = (_Float16)ur[i];
        a_rh[i] = h;
        a_rl[i] = (_Float16)(ur[i] - (float)h);
        const _Float16 g = (_Float16)ui[i];
        a_ih[i] = g;
        a_il[i] = (_Float16)(ui[i] - (float)g);
    }

    const int rs = lg ^ ((l15 >> 1) & 3);                    // lane-constant read swizzle
    const _Float16* rp = Sb + (wave * 64 + l15) * 32 + rs * 8;
    const int obase = blockIdx.x * TPB + wave * 64;

    #pragma unroll
    for (int T = 0; T < 4; T++) {
        const half8 b = *reinterpret_cast<const half8*>(rp + T * 512);
        f32x4 cre = {0.f, 0.f, 0.f, 0.f}, cim = {0.f, 0.f, 0.f, 0.f};
        cre = __builtin_amdgcn_mfma_f32_16x16x32_f16(a_rh, b, cre, 0, 0, 0);
        cre = __builtin_amdgcn_mfma_f32_16x16x32_f16(a_rl, b, cre, 0, 0, 0);
        cim = __builtin_amdgcn_mfma_f32_16x16x32_f16(a_ih, b, cim, 0, 0, 0);
        cim = __builtin_amdgcn_mfma_f32_16x16x32_f16(a_il, b, cim, 0, 0, 0);

        // p_r = |amp_{j=4*lg+r}|^2 for sample s=l15 (of this tile)
        const float q0 = fmaf(cre[0], cre[0], cim[0] * cim[0]);
        const float q1 = fmaf(cre[1], cre[1], cim[1] * cim[1]);
        const float q2 = fmaf(cre[2], cre[2], cim[2] * cim[2]);
        const float q3 = fmaf(cre[3], cre[3], cim[3] * cim[3]);
        // j = 4*lg + r:  bit3(j)=lg&2, bit2(j)=lg&1, bit1(j)=r&2, bit0(j)=r&1
        const float s01 = q0 + q1, s23 = q2 + q3;
        const float t = s01 + s23;                 // sum over r
        const float u = s01 - s23;                 // Z2 partial (sign by r&2)
        const float v = (q0 - q1) + (q2 - q3);     // Z3 partial (sign by r&1)
        // stage 1: xor 16 (lg^1)
        const float tx = __shfl_xor(t, 16);
        const float t1 = t + tx;
        const float z1 = t - tx;                   // valid in lg even
        const float u1 = u + __shfl_xor(u, 16);
        const float v1 = v + __shfl_xor(v, 16);
        // stage 2: xor 32 (lg^2); results valid in lanes 0..15, which store
        const float z0  = t1 - __shfl_xor(t1, 32);
        const float z1f = z1 + __shfl_xor(z1, 32);
        const float z2  = u1 + __shfl_xor(u1, 32);
        const float z3  = v1 + __shfl_xor(v1, 32);

        if (lane < 16)
            reinterpret_cast<float4*>(out)[obase + T * 16 + l15] =
                make_float4(z0, z1f, z2, z3);
    }
}

extern "C" void kernel_launch(void* const* d_in, const int* in_sizes, int n_in,
                              void* d_out, int out_size, void* d_ws, size_t ws_size,
                              hipStream_t stream) {
    const float* x = (const float*)d_in[0];
    const float* w = (const float*)d_in[1];
    float* out = (float*)d_out;
    (void)d_ws; (void)ws_size;

    const int grid = BATCH / TPB;  // 2048 blocks, 1 sample/thread
    qfused_kernel<<<grid, TPB, 0, stream>>>(x, w, out);
}